// Round 11
// baseline (726.005 us; speedup 1.0000x reference)
//
#include <hip/hip_runtime.h>
#include <hip/hip_cooperative_groups.h>
namespace cg = cooperative_groups;

typedef __attribute__((ext_vector_type(8))) __bf16 bf16x8;
typedef __attribute__((ext_vector_type(4))) float f32x4;

union Frag { unsigned short u[8]; bf16x8 b; };

__device__ __forceinline__ unsigned short rne_bf16(float x) {
    unsigned int u = __float_as_uint(x);
    return (unsigned short)((u + 0x7fffu + ((u >> 16) & 1u)) >> 16);
}
__device__ __forceinline__ float bf16_to_f(unsigned short h) {
    return __uint_as_float(((unsigned int)h) << 16);
}

#define MFMA16 __builtin_amdgcn_mfma_f32_16x16x32_bf16
#define SBSH 10
#define SBN 1024
#define SBCAP 13056
#define BINCHUNK 4096
#define NWFRAG (3 * 2 * 2 * 4 * 64 * 8)

// =============================== MEGA KERNEL ================================
// Phase A: bin (blocks < nBin) + prep (blocks >= nBin)
// Phase B: per-super-bucket CSR (hist+scan+fill -> srcs2), 256-thr blocks
// Phase C: gather, wave per node (grid-stride persistent waves)
// Phase D: MFMA MLP, wave per 32-node tile
__global__ __launch_bounds__(256, 4) void mega_kernel(
    const float* __restrict__ nf, const int* __restrict__ src,
    const int* __restrict__ dst, const int* __restrict__ gids,
    const float* __restrict__ Wg, const float* __restrict__ bg,
    const float* __restrict__ Wr, const float* __restrict__ br,
    const float* __restrict__ Wi, const float* __restrict__ bi,
    const float* __restrict__ Wo, const float* __restrict__ bo,
    const float* __restrict__ Wp, const float* __restrict__ bp,
    int* __restrict__ gcursor, int* __restrict__ binned,
    int* __restrict__ srcs2, int2* __restrict__ nodeTab,
    unsigned short* __restrict__ nfb, unsigned short* __restrict__ aggb,
    unsigned short* __restrict__ wfrag, float* __restrict__ wfold,
    float* __restrict__ c0p, float* __restrict__ out,
    int nBin, int nE, int nbS, int out_size, int nNodes, int nTiles)
{
    __shared__ float smemf[4 * 2176];          // 34816 B, reused per phase
    int* smi = (int*)smemf;
    cg::grid_group grid = cg::this_grid();
    const int t = threadIdx.x;
    const int nblk = (int)gridDim.x;
    const int wave = t >> 6, lane = t & 63;

    // ---------------- Phase A ----------------
    if ((int)blockIdx.x < nBin) {
        int* lhist = smi; int* lbase = smi + 128; int* lpos = smi + 256;
        for (int c = blockIdx.x; c < nBin; c += nblk) {
            for (int i = t; i < nbS; i += 256) { lhist[i] = 0; lpos[i] = 0; }
            __syncthreads();
            const int e0 = c * BINCHUNK;
            const int e1 = min(e0 + BINCHUNK, nE);
            for (int e = e0 + t; e < e1; e += 256)
                atomicAdd(&lhist[dst[e] >> SBSH], 1);
            __syncthreads();
            for (int i = t; i < nbS; i += 256) {
                int cc = lhist[i];
                lbase[i] = cc ? atomicAdd(&gcursor[i], cc) : 0;
            }
            __syncthreads();
            for (int e = e0 + t; e < e1; e += 256) {
                int d = dst[e];
                int sb = d >> SBSH;
                int p = atomicAdd(&lpos[sb], 1);
                int gp = lbase[sb] + p;
                if (gp < SBCAP) binned[sb * SBCAP + gp] = (src[e] << SBSH) | (d & (SBN - 1));
            }
            __syncthreads();
        }
    } else {
        const int tp = ((int)blockIdx.x - nBin) * 256 + t;
        const int nth = (nblk - nBin) * 256;
        const float4* nf4 = (const float4*)nf;
        ushort4* nfb4 = (ushort4*)nfb;
        const int nQ = nNodes * 16;
        for (int i = tp; i < nQ; i += nth) {
            float4 v = nf4[i];
            ushort4 o;
            o.x = rne_bf16(v.x); o.y = rne_bf16(v.y);
            o.z = rne_bf16(v.z); o.w = rne_bf16(v.w);
            nfb4[i] = o;
        }
        const float* Ws[3] = {Wg, Wr, Wi};
        for (int idx = tp; idx < NWFRAG; idx += nth) {
            int j = idx & 7, ln = (idx >> 3) & 63, nt = (idx >> 9) & 3;
            int kt = (idx >> 11) & 1, part = (idx >> 12) & 1, mat = idx >> 13;
            int k = kt * 32 + ((ln >> 4) << 3) + j;
            int n = nt * 16 + (ln & 15);
            float w = Ws[mat][k * 64 + n];
            unsigned short hi = rne_bf16(w);
            wfrag[idx] = (part == 0) ? hi : rne_bf16(w - bf16_to_f(hi));
        }
        if (tp < 64) {
            float s = 0.f;
            for (int j = 0; j < 128; ++j) s += Wo[tp * 128 + j] * Wp[j];
            wfold[tp] = s;
        }
        if (tp == 0) {
            float s = 0.f;
            for (int j = 0; j < 128; ++j) s += bo[j] * Wp[j];
            c0p[0] = s;
        }
        if (tp < out_size) out[tp] = bp[0];
    }
    __threadfence();
    grid.sync();

    // ---------------- Phase B ----------------
    {
        int* deg = smi; int* cur = smi + 1024; int* tsum = smi + 2048;
        for (int b = blockIdx.x; b < nbS; b += nblk) {
            const int cnt = min(gcursor[b], SBCAP);
            const int bb = b * SBCAP;
            for (int j = t; j < SBN; j += 256) deg[j] = 0;
            __syncthreads();
            for (int i = t; i < cnt; i += 256)
                atomicAdd(&deg[binned[bb + i] & (SBN - 1)], 1);
            __syncthreads();
            int d0 = deg[4 * t], d1 = deg[4 * t + 1];
            int d2 = deg[4 * t + 2], d3 = deg[4 * t + 3];
            int s = d0 + d1 + d2 + d3;
            tsum[t] = s;
            __syncthreads();
            for (int off = 1; off < 256; off <<= 1) {
                int v = (t >= off) ? tsum[t - off] : 0;
                __syncthreads();
                tsum[t] += v;
                __syncthreads();
            }
            int base = tsum[t] - s;
            int e0 = base, e1 = base + d0, e2 = e1 + d1, e3 = e2 + d2;
            cur[4 * t] = e0; cur[4 * t + 1] = e1;
            cur[4 * t + 2] = e2; cur[4 * t + 3] = e3;
            int node = b * SBN + 4 * t;
            if (node + 0 < nNodes) nodeTab[node + 0] = make_int2(bb + e0, d0);
            if (node + 1 < nNodes) nodeTab[node + 1] = make_int2(bb + e1, d1);
            if (node + 2 < nNodes) nodeTab[node + 2] = make_int2(bb + e2, d2);
            if (node + 3 < nNodes) nodeTab[node + 3] = make_int2(bb + e3, d3);
            __syncthreads();
            for (int i = t; i < cnt; i += 256) {
                int p = binned[bb + i];
                int pos = atomicAdd(&cur[p & (SBN - 1)], 1);
                srcs2[bb + pos] = p >> SBSH;
            }
            __syncthreads();
        }
    }
    __threadfence();
    grid.sync();

    // ---------------- Phase C: gather ----------------
    {
        const int half = lane >> 5, cp = lane & 31;
        const ushort2* nfb2 = (const ushort2*)nfb;
        for (int wid = blockIdx.x * 4 + wave; wid < nNodes; wid += nblk * 4) {
            int2 sd = nodeTab[wid];
            int base = sd.x, d = sd.y;
            float ax = 0.f, ay = 0.f;
            int k = half;
            for (; k + 8 <= d; k += 8) {
                int s0 = srcs2[base + k],     s1 = srcs2[base + k + 2];
                int s2 = srcs2[base + k + 4], s3 = srcs2[base + k + 6];
                ushort2 v0 = nfb2[(long)s0 * 32 + cp];
                ushort2 v1 = nfb2[(long)s1 * 32 + cp];
                ushort2 v2 = nfb2[(long)s2 * 32 + cp];
                ushort2 v3 = nfb2[(long)s3 * 32 + cp];
                ax += (bf16_to_f(v0.x) + bf16_to_f(v1.x)) + (bf16_to_f(v2.x) + bf16_to_f(v3.x));
                ay += (bf16_to_f(v0.y) + bf16_to_f(v1.y)) + (bf16_to_f(v2.y) + bf16_to_f(v3.y));
            }
            for (; k < d; k += 2) {
                int s = srcs2[base + k];
                ushort2 v = nfb2[(long)s * 32 + cp];
                ax += bf16_to_f(v.x); ay += bf16_to_f(v.y);
            }
            ax += __shfl_xor(ax, 32, 64);
            ay += __shfl_xor(ay, 32, 64);
            if (half == 0) {
                ushort2 o; o.x = rne_bf16(ax); o.y = rne_bf16(ay);
                ((ushort2*)aggb)[(long)wid * 32 + cp] = o;
            }
        }
    }
    __threadfence();
    grid.sync();

    // ---------------- Phase D: MFMA MLP ----------------
    {
        float* hs = smemf + wave * 2176;       // 32*68 per wave
        const int mrow = lane & 15, quad = lane >> 4;
        const unsigned short* wl0 = wfrag + lane * 8;
        const float c0 = c0p[0];
        for (int wid = blockIdx.x * 4 + wave; wid < nTiles; wid += nblk * 4) {
            const int base = wid * 32;

            Frag aA[2][2], aN[2][2];
            #pragma unroll
            for (int rt = 0; rt < 2; ++rt) {
                const unsigned short* rowA = aggb + (long)(base + rt * 16 + mrow) * 64;
                const unsigned short* rowN = nfb  + (long)(base + rt * 16 + mrow) * 64;
                #pragma unroll
                for (int kt = 0; kt < 2; ++kt) {
                    aA[rt][kt].b = *(const bf16x8*)(rowA + kt * 32 + quad * 8);
                    aN[rt][kt].b = *(const bf16x8*)(rowN + kt * 32 + quad * 8);
                }
            }
            auto WF = [&](int mat, int part, int kt, int nt) -> bf16x8 {
                return *(const bf16x8*)(wl0 + (size_t)((((mat * 2 + part) * 2 + kt) * 4 + nt) * 64) * 8);
            };

            f32x4 accA[2][4], accR[2][4];
            #pragma unroll
            for (int rt = 0; rt < 2; ++rt)
                #pragma unroll
                for (int nt = 0; nt < 4; ++nt) {
                    accA[rt][nt] = (f32x4){0.f, 0.f, 0.f, 0.f};
                    accR[rt][nt] = (f32x4){0.f, 0.f, 0.f, 0.f};
                }
            #pragma unroll
            for (int nt = 0; nt < 4; ++nt)
                #pragma unroll
                for (int kt = 0; kt < 2; ++kt) {
                    bf16x8 gh = WF(0, 0, kt, nt), gl = WF(0, 1, kt, nt);
                    bf16x8 rh = WF(1, 0, kt, nt), rl = WF(1, 1, kt, nt);
                    #pragma unroll
                    for (int rt = 0; rt < 2; ++rt) {
                        accA[rt][nt] = MFMA16(aA[rt][kt].b, gh, accA[rt][nt], 0, 0, 0);
                        accA[rt][nt] = MFMA16(aA[rt][kt].b, gl, accA[rt][nt], 0, 0, 0);
                        accR[rt][nt] = MFMA16(aN[rt][kt].b, rh, accR[rt][nt], 0, 0, 0);
                        accR[rt][nt] = MFMA16(aN[rt][kt].b, rl, accR[rt][nt], 0, 0, 0);
                    }
                }

            #pragma unroll
            for (int nt = 0; nt < 4; ++nt) {
                float bgv = bg[nt * 16 + mrow], brv = br[nt * 16 + mrow];
                #pragma unroll
                for (int rt = 0; rt < 2; ++rt)
                    #pragma unroll
                    for (int r = 0; r < 4; ++r) {
                        float h = fmaxf(accA[rt][nt][r] + bgv, 0.f)
                                + fmaxf(accR[rt][nt][r] + brv, 0.f);
                        hs[(rt * 16 + quad * 4 + r) * 68 + nt * 16 + mrow] = h;
                    }
            }
            __builtin_amdgcn_wave_barrier();

            Frag aH[2][2];
            #pragma unroll
            for (int rt = 0; rt < 2; ++rt)
                #pragma unroll
                for (int kt = 0; kt < 2; ++kt) {
                    const float* hp = hs + (rt * 16 + mrow) * 68 + kt * 32 + quad * 8;
                    float4 v0 = *(const float4*)hp;
                    float4 v1 = *(const float4*)(hp + 4);
                    aH[rt][kt].u[0] = rne_bf16(v0.x); aH[rt][kt].u[1] = rne_bf16(v0.y);
                    aH[rt][kt].u[2] = rne_bf16(v0.z); aH[rt][kt].u[3] = rne_bf16(v0.w);
                    aH[rt][kt].u[4] = rne_bf16(v1.x); aH[rt][kt].u[5] = rne_bf16(v1.y);
                    aH[rt][kt].u[6] = rne_bf16(v1.z); aH[rt][kt].u[7] = rne_bf16(v1.w);
                }
            __builtin_amdgcn_wave_barrier();
            f32x4 accH[2][4];
            #pragma unroll
            for (int rt = 0; rt < 2; ++rt)
                #pragma unroll
                for (int nt = 0; nt < 4; ++nt)
                    accH[rt][nt] = (f32x4){0.f, 0.f, 0.f, 0.f};
            #pragma unroll
            for (int nt = 0; nt < 4; ++nt)
                #pragma unroll
                for (int kt = 0; kt < 2; ++kt) {
                    bf16x8 ih = WF(2, 0, kt, nt), il = WF(2, 1, kt, nt);
                    #pragma unroll
                    for (int rt = 0; rt < 2; ++rt) {
                        accH[rt][nt] = MFMA16(aH[rt][kt].b, ih, accH[rt][nt], 0, 0, 0);
                        accH[rt][nt] = MFMA16(aH[rt][kt].b, il, accH[rt][nt], 0, 0, 0);
                    }
                }

            float p[2][4];
            #pragma unroll
            for (int rt = 0; rt < 2; ++rt)
                #pragma unroll
                for (int r = 0; r < 4; ++r) p[rt][r] = 0.f;
            #pragma unroll
            for (int nt = 0; nt < 4; ++nt) {
                float biv = bi[nt * 16 + mrow], wfv = wfold[nt * 16 + mrow];
                #pragma unroll
                for (int rt = 0; rt < 2; ++rt)
                    #pragma unroll
                    for (int r = 0; r < 4; ++r)
                        p[rt][r] += fmaxf(accH[rt][nt][r] + biv, 0.f) * wfv;
            }
            #pragma unroll
            for (int m = 1; m <= 8; m <<= 1)
                #pragma unroll
                for (int rt = 0; rt < 2; ++rt)
                    #pragma unroll
                    for (int r = 0; r < 4; ++r)
                        p[rt][r] += __shfl_xor(p[rt][r], m, 64);
            #pragma unroll
            for (int rt = 0; rt < 2; ++rt)
                #pragma unroll
                for (int r = 0; r < 4; ++r) p[rt][r] += c0;

            int gself = gids[base + (lane & 31)];
            int g0 = __shfl(gself, 0, 64);
            if (__all(gself == g0)) {
                float pv = 0.f;
                if (mrow == 0) {
                    #pragma unroll
                    for (int rt = 0; rt < 2; ++rt)
                        #pragma unroll
                        for (int r = 0; r < 4; ++r) pv += p[rt][r];
                }
                pv += __shfl_xor(pv, 16, 64);
                pv += __shfl_xor(pv, 32, 64);
                if (lane == 0) atomicAdd(out + g0, pv);
            } else if (mrow == 0) {
                #pragma unroll
                for (int rt = 0; rt < 2; ++rt)
                    #pragma unroll
                    for (int r = 0; r < 4; ++r)
                        atomicAdd(out + gids[base + rt * 16 + quad * 4 + r], p[rt][r]);
            }
            __builtin_amdgcn_wave_barrier();
        }
    }
}

// ======================= FALLBACK (R10 split pipeline) ======================
__global__ __launch_bounds__(256) void prepbinA_kernel(
    const float* __restrict__ nf, const int* __restrict__ src,
    const int* __restrict__ dst,
    const float* __restrict__ Wg, const float* __restrict__ Wr,
    const float* __restrict__ Wi, const float* __restrict__ Wo,
    const float* __restrict__ bo, const float* __restrict__ Wp,
    const float* __restrict__ bp,
    unsigned short* __restrict__ nfb, unsigned short* __restrict__ wfrag,
    float* __restrict__ wfold, float* __restrict__ c0, float* __restrict__ out,
    int* __restrict__ gcursor, int* __restrict__ binned,
    int nBin, int nE, int nbS, int out_size, int nNodes) {
    __shared__ int lhist[128], lbase[128], lpos[128];
    const int t = threadIdx.x;
    if ((int)blockIdx.x < nBin) {
        for (int i = t; i < nbS; i += 256) { lhist[i] = 0; lpos[i] = 0; }
        __syncthreads();
        const int e0 = blockIdx.x * BINCHUNK;
        const int e1 = min(e0 + BINCHUNK, nE);
        for (int e = e0 + t; e < e1; e += 256)
            atomicAdd(&lhist[dst[e] >> SBSH], 1);
        __syncthreads();
        for (int i = t; i < nbS; i += 256) {
            int c = lhist[i];
            lbase[i] = c ? atomicAdd(&gcursor[i], c) : 0;
        }
        __syncthreads();
        for (int e = e0 + t; e < e1; e += 256) {
            int d = dst[e];
            int sb = d >> SBSH;
            int p = atomicAdd(&lpos[sb], 1);
            int gp = lbase[sb] + p;
            if (gp < SBCAP) binned[sb * SBCAP + gp] = (src[e] << SBSH) | (d & (SBN - 1));
        }
        return;
    }
    const int tp = ((int)blockIdx.x - nBin) * 256 + t;
    const int nth = ((int)gridDim.x - nBin) * 256;
    const float4* nf4 = (const float4*)nf;
    ushort4* nfb4 = (ushort4*)nfb;
    const int nQ = nNodes * 16;
    for (int i = tp; i < nQ; i += nth) {
        float4 v = nf4[i];
        ushort4 o;
        o.x = rne_bf16(v.x); o.y = rne_bf16(v.y);
        o.z = rne_bf16(v.z); o.w = rne_bf16(v.w);
        nfb4[i] = o;
    }
    const float* Ws[3] = {Wg, Wr, Wi};
    for (int idx = tp; idx < NWFRAG; idx += nth) {
        int j = idx & 7, lane = (idx >> 3) & 63, nt = (idx >> 9) & 3;
        int kt = (idx >> 11) & 1, part = (idx >> 12) & 1, mat = idx >> 13;
        int k = kt * 32 + ((lane >> 4) << 3) + j;
        int n = nt * 16 + (lane & 15);
        float w = Ws[mat][k * 64 + n];
        unsigned short hi = rne_bf16(w);
        wfrag[idx] = (part == 0) ? hi : rne_bf16(w - bf16_to_f(hi));
    }
    if (tp < 64) {
        float s = 0.f;
        for (int j = 0; j < 128; ++j) s += Wo[tp * 128 + j] * Wp[j];
        wfold[tp] = s;
    }
    if (tp == 0) {
        float s = 0.f;
        for (int j = 0; j < 128; ++j) s += bo[j] * Wp[j];
        c0[0] = s;
    }
    if (tp < out_size) out[tp] = bp[0];
}

__global__ __launch_bounds__(1024) void segB_kernel(
    const int* __restrict__ binned, const int* __restrict__ gcursor,
    int* __restrict__ srcs2, int2* __restrict__ nodeTab, int nNodes) {
    __shared__ int deg[SBN], sc[SBN], cur[SBN];
    const int b = blockIdx.x, t = threadIdx.x;
    const int cnt = min(gcursor[b], SBCAP);
    const int bb = b * SBCAP;
    deg[t] = 0;
    __syncthreads();
    for (int i = t; i < cnt; i += 1024)
        atomicAdd(&deg[binned[bb + i] & (SBN - 1)], 1);
    __syncthreads();
    sc[t] = deg[t];
    __syncthreads();
    #pragma unroll
    for (int s = 1; s < SBN; s <<= 1) {
        int v = (t >= s) ? sc[t - s] : 0;
        __syncthreads();
        sc[t] += v;
        __syncthreads();
    }
    {
        int excl = sc[t] - deg[t];
        cur[t] = excl;
        int node = b * SBN + t;
        if (node < nNodes) nodeTab[node] = make_int2(bb + excl, deg[t]);
    }
    __syncthreads();
    for (int i = t; i < cnt; i += 1024) {
        int p = binned[bb + i];
        int pos = atomicAdd(&cur[p & (SBN - 1)], 1);
        srcs2[bb + pos] = p >> SBSH;
    }
}

__global__ __launch_bounds__(256) void gather_kernel(
    const unsigned short* __restrict__ nfb, const int2* __restrict__ nodeTab,
    const int* __restrict__ srcs, unsigned short* __restrict__ aggb, int nNodes) {
    int wid = blockIdx.x * 4 + (threadIdx.x >> 6);
    if (wid >= nNodes) return;
    int lane = threadIdx.x & 63;
    int half = lane >> 5;
    int cp = lane & 31;
    int2 sd = nodeTab[wid];
    int base = sd.x, d = sd.y;
    const ushort2* nfb2 = (const ushort2*)nfb;
    float ax = 0.f, ay = 0.f;
    int k = half;
    for (; k + 8 <= d; k += 8) {
        int s0 = srcs[base + k],     s1 = srcs[base + k + 2];
        int s2 = srcs[base + k + 4], s3 = srcs[base + k + 6];
        ushort2 v0 = nfb2[(long)s0 * 32 + cp];
        ushort2 v1 = nfb2[(long)s1 * 32 + cp];
        ushort2 v2 = nfb2[(long)s2 * 32 + cp];
        ushort2 v3 = nfb2[(long)s3 * 32 + cp];
        ax += (bf16_to_f(v0.x) + bf16_to_f(v1.x)) + (bf16_to_f(v2.x) + bf16_to_f(v3.x));
        ay += (bf16_to_f(v0.y) + bf16_to_f(v1.y)) + (bf16_to_f(v2.y) + bf16_to_f(v3.y));
    }
    for (; k < d; k += 2) {
        int s = srcs[base + k];
        ushort2 v = nfb2[(long)s * 32 + cp];
        ax += bf16_to_f(v.x); ay += bf16_to_f(v.y);
    }
    ax += __shfl_xor(ax, 32, 64);
    ay += __shfl_xor(ay, 32, 64);
    if (half == 0) {
        ushort2 o; o.x = rne_bf16(ax); o.y = rne_bf16(ay);
        ((ushort2*)aggb)[(long)wid * 32 + cp] = o;
    }
}

__global__ __launch_bounds__(256) void mlp_kernel(
    const unsigned short* __restrict__ aggb, const unsigned short* __restrict__ nfb,
    const int* __restrict__ gids, const unsigned short* __restrict__ wfrag,
    const float* __restrict__ bg, const float* __restrict__ br,
    const float* __restrict__ bi, const float* __restrict__ wfold,
    const float* __restrict__ c0p, float* __restrict__ out, int nTiles) {
    __shared__ float hs_all[4][32 * 68];
    const int wave = threadIdx.x >> 6, lane = threadIdx.x & 63;
    const int wid = blockIdx.x * 4 + wave;
    if (wid >= nTiles) return;
    float* hs = hs_all[wave];
    const int base = wid * 32;
    const int mrow = lane & 15, quad = lane >> 4;

    Frag aA[2][2], aN[2][2];
    #pragma unroll
    for (int rt = 0; rt < 2; ++rt) {
        const unsigned short* rowA = aggb + (long)(base + rt * 16 + mrow) * 64;
        const unsigned short* rowN = nfb  + (long)(base + rt * 16 + mrow) * 64;
        #pragma unroll
        for (int kt = 0; kt < 2; ++kt) {
            aA[rt][kt].b = *(const bf16x8*)(rowA + kt * 32 + quad * 8);
            aN[rt][kt].b = *(const bf16x8*)(rowN + kt * 32 + quad * 8);
        }
    }
    const unsigned short* wl0 = wfrag + lane * 8;
    auto WF = [&](int mat, int part, int kt, int nt) -> bf16x8 {
        return *(const bf16x8*)(wl0 + (size_t)((((mat * 2 + part) * 2 + kt) * 4 + nt) * 64) * 8);
    };
    f32x4 accA[2][4], accR[2][4];
    #pragma unroll
    for (int rt = 0; rt < 2; ++rt)
        #pragma unroll
        for (int nt = 0; nt < 4; ++nt) {
            accA[rt][nt] = (f32x4){0.f, 0.f, 0.f, 0.f};
            accR[rt][nt] = (f32x4){0.f, 0.f, 0.f, 0.f};
        }
    #pragma unroll
    for (int nt = 0; nt < 4; ++nt)
        #pragma unroll
        for (int kt = 0; kt < 2; ++kt) {
            bf16x8 gh = WF(0, 0, kt, nt), gl = WF(0, 1, kt, nt);
            bf16x8 rh = WF(1, 0, kt, nt), rl = WF(1, 1, kt, nt);
            #pragma unroll
            for (int rt = 0; rt < 2; ++rt) {
                accA[rt][nt] = MFMA16(aA[rt][kt].b, gh, accA[rt][nt], 0, 0, 0);
                accA[rt][nt] = MFMA16(aA[rt][kt].b, gl, accA[rt][nt], 0, 0, 0);
                accR[rt][nt] = MFMA16(aN[rt][kt].b, rh, accR[rt][nt], 0, 0, 0);
                accR[rt][nt] = MFMA16(aN[rt][kt].b, rl, accR[rt][nt], 0, 0, 0);
            }
        }
    #pragma unroll
    for (int nt = 0; nt < 4; ++nt) {
        float bgv = bg[nt * 16 + mrow], brv = br[nt * 16 + mrow];
        #pragma unroll
        for (int rt = 0; rt < 2; ++rt)
            #pragma unroll
            for (int r = 0; r < 4; ++r) {
                float h = fmaxf(accA[rt][nt][r] + bgv, 0.f)
                        + fmaxf(accR[rt][nt][r] + brv, 0.f);
                hs[(rt * 16 + quad * 4 + r) * 68 + nt * 16 + mrow] = h;
            }
    }
    __builtin_amdgcn_wave_barrier();
    Frag aH[2][2];
    #pragma unroll
    for (int rt = 0; rt < 2; ++rt)
        #pragma unroll
        for (int kt = 0; kt < 2; ++kt) {
            const float* hp = hs + (rt * 16 + mrow) * 68 + kt * 32 + quad * 8;
            float4 v0 = *(const float4*)hp;
            float4 v1 = *(const float4*)(hp + 4);
            aH[rt][kt].u[0] = rne_bf16(v0.x); aH[rt][kt].u[1] = rne_bf16(v0.y);
            aH[rt][kt].u[2] = rne_bf16(v0.z); aH[rt][kt].u[3] = rne_bf16(v0.w);
            aH[rt][kt].u[4] = rne_bf16(v1.x); aH[rt][kt].u[5] = rne_bf16(v1.y);
            aH[rt][kt].u[6] = rne_bf16(v1.z); aH[rt][kt].u[7] = rne_bf16(v1.w);
        }
    f32x4 accH[2][4];
    #pragma unroll
    for (int rt = 0; rt < 2; ++rt)
        #pragma unroll
        for (int nt = 0; nt < 4; ++nt)
            accH[rt][nt] = (f32x4){0.f, 0.f, 0.f, 0.f};
    #pragma unroll
    for (int nt = 0; nt < 4; ++nt)
        #pragma unroll
        for (int kt = 0; kt < 2; ++kt) {
            bf16x8 ih = WF(2, 0, kt, nt), il = WF(2, 1, kt, nt);
            #pragma unroll
            for (int rt = 0; rt < 2; ++rt) {
                accH[rt][nt] = MFMA16(aH[rt][kt].b, ih, accH[rt][nt], 0, 0, 0);
                accH[rt][nt] = MFMA16(aH[rt][kt].b, il, accH[rt][nt], 0, 0, 0);
            }
        }
    float p[2][4];
    #pragma unroll
    for (int rt = 0; rt < 2; ++rt)
        #pragma unroll
        for (int r = 0; r < 4; ++r) p[rt][r] = 0.f;
    #pragma unroll
    for (int nt = 0; nt < 4; ++nt) {
        float biv = bi[nt * 16 + mrow], wfv = wfold[nt * 16 + mrow];
        #pragma unroll
        for (int rt = 0; rt < 2; ++rt)
            #pragma unroll
            for (int r = 0; r < 4; ++r)
                p[rt][r] += fmaxf(accH[rt][nt][r] + biv, 0.f) * wfv;
    }
    #pragma unroll
    for (int m = 1; m <= 8; m <<= 1)
        #pragma unroll
        for (int rt = 0; rt < 2; ++rt)
            #pragma unroll
            for (int r = 0; r < 4; ++r)
                p[rt][r] += __shfl_xor(p[rt][r], m, 64);
    const float c0 = c0p[0];
    #pragma unroll
    for (int rt = 0; rt < 2; ++rt)
        #pragma unroll
        for (int r = 0; r < 4; ++r) p[rt][r] += c0;
    int gself = gids[base + (lane & 31)];
    int g0 = __shfl(gself, 0, 64);
    if (__all(gself == g0)) {
        float pv = 0.f;
        if (mrow == 0) {
            #pragma unroll
            for (int rt = 0; rt < 2; ++rt)
                #pragma unroll
                for (int r = 0; r < 4; ++r) pv += p[rt][r];
        }
        pv += __shfl_xor(pv, 16, 64);
        pv += __shfl_xor(pv, 32, 64);
        if (lane == 0) atomicAdd(out + g0, pv);
    } else if (mrow == 0) {
        #pragma unroll
        for (int rt = 0; rt < 2; ++rt)
            #pragma unroll
            for (int r = 0; r < 4; ++r)
                atomicAdd(out + gids[base + rt * 16 + quad * 4 + r], p[rt][r]);
    }
}

extern "C" void kernel_launch(void* const* d_in, const int* in_sizes, int n_in,
                              void* d_out, int out_size, void* d_ws, size_t ws_size,
                              hipStream_t stream) {
    const float* node_feats = (const float*)d_in[0];
    const int* src  = (const int*)d_in[2];
    const int* dst  = (const int*)d_in[3];
    const int* gids = (const int*)d_in[4];
    const float* Wg = (const float*)d_in[5];
    const float* bg = (const float*)d_in[6];
    const float* Wr = (const float*)d_in[7];
    const float* br = (const float*)d_in[8];
    const float* Wi = (const float*)d_in[9];
    const float* bi = (const float*)d_in[10];
    const float* Wo = (const float*)d_in[11];
    const float* bo = (const float*)d_in[12];
    const float* Wp = (const float*)d_in[13];
    const float* bp = (const float*)d_in[14];
    float* out = (float*)d_out;

    const int nNodes = in_sizes[0] / 64;              // 100000
    const int nE = in_sizes[2];
    const int nbS = (nNodes + SBN - 1) / SBN;         // 98
    const int nBin = (nE + BINCHUNK - 1) / BINCHUNK;  // 293
    const int nTiles = (nNodes + 31) / 32;            // 3125

    // ws: gcursor[128] | binned[nbS*SBCAP] | srcs2[nbS*SBCAP] | nodeTab[N] int2
    //   | nfb[N*64] bf16 | aggb[N*64] bf16 | wfrag | wfold[64] | c0[1]
    int* gcursor = (int*)d_ws;
    int* binned  = gcursor + 128;
    int* srcs2   = binned + (size_t)nbS * SBCAP;
    int2* nodeTab = (int2*)(srcs2 + (size_t)nbS * SBCAP);
    unsigned short* nfb  = (unsigned short*)(nodeTab + nNodes);
    unsigned short* aggb = nfb + (size_t)nNodes * 64;
    unsigned short* wfrag = aggb + (size_t)nNodes * 64;
    float* wfold = (float*)(wfrag + NWFRAG);
    float* c0 = wfold + 64;

    hipMemsetAsync(gcursor, 0, 128 * sizeof(int), stream);

    // cooperative grid sizing (host-side queries; stream-safe, deterministic)
    int dev = 0;
    hipGetDevice(&dev);
    int nCU = 256;
    hipDeviceGetAttribute(&nCU, hipDeviceAttributeMultiprocessorCount, dev);
    int occ = 0;
    hipOccupancyMaxActiveBlocksPerMultiprocessor(&occ, mega_kernel, 256, 0);
    if (occ < 1) occ = 1;
    long gridL = (long)occ * nCU;
    int grid = (int)(gridL > 2048 ? 2048 : gridL);

    hipError_t err = hipErrorUnknown;
    if (grid > nBin + 64) {
        void* args[] = {
            (void*)&node_feats, (void*)&src, (void*)&dst, (void*)&gids,
            (void*)&Wg, (void*)&bg, (void*)&Wr, (void*)&br,
            (void*)&Wi, (void*)&bi, (void*)&Wo, (void*)&bo,
            (void*)&Wp, (void*)&bp,
            (void*)&gcursor, (void*)&binned, (void*)&srcs2, (void*)&nodeTab,
            (void*)&nfb, (void*)&aggb, (void*)&wfrag, (void*)&wfold,
            (void*)&c0, (void*)&out,
            (void*)&nBin, (void*)&nE, (void*)&nbS, (void*)&out_size,
            (void*)&nNodes, (void*)&nTiles };
        err = hipLaunchCooperativeKernel((void*)mega_kernel, dim3(grid), dim3(256),
                                         args, 0, stream);
    }
    if (err != hipSuccess) {
        // fallback: R10 split pipeline
        prepbinA_kernel<<<nBin + 512, 256, 0, stream>>>(
            node_feats, src, dst, Wg, Wr, Wi, Wo, bo, Wp, bp,
            nfb, wfrag, wfold, c0, out, gcursor, binned,
            nBin, nE, nbS, out_size, nNodes);
        segB_kernel<<<nbS, 1024, 0, stream>>>(binned, gcursor, srcs2, nodeTab, nNodes);
        gather_kernel<<<(nNodes + 3) / 4, 256, 0, stream>>>(nfb, nodeTab, srcs2, aggb, nNodes);
        mlp_kernel<<<(nTiles + 3) / 4, 256, 0, stream>>>(aggb, nfb, gids, wfrag,
            bg, br, bi, wfold, c0, out, nTiles);
    }
}

// Round 12
// 218.932 us; speedup vs baseline: 3.3161x; 3.3161x over previous
//
#include <hip/hip_runtime.h>

typedef __attribute__((ext_vector_type(8))) __bf16 bf16x8;
typedef __attribute__((ext_vector_type(4))) float f32x4;

union Frag { unsigned short u[8]; bf16x8 b; };

__device__ __forceinline__ unsigned short rne_bf16(float x) {
    unsigned int u = __float_as_uint(x);
    return (unsigned short)((u + 0x7fffu + ((u >> 16) & 1u)) >> 16);
}
__device__ __forceinline__ float bf16_to_f(unsigned short h) {
    return __uint_as_float(((unsigned int)h) << 16);
}

#define MFMA16 __builtin_amdgcn_mfma_f32_16x16x32_bf16
#define SBSH 10
#define SBN 1024
#define SBCAP 13056
#define BINCHUNK 4096
#define NWFRAG (3 * 2 * 2 * 4 * 64 * 8)

// ---- prepbinA: sorted-write binning (LDS counting sort) + prep -------------
__global__ __launch_bounds__(256) void prepbinA_kernel(
    const float* __restrict__ nf, const int* __restrict__ src,
    const int* __restrict__ dst,
    const float* __restrict__ Wg, const float* __restrict__ Wr,
    const float* __restrict__ Wi, const float* __restrict__ Wo,
    const float* __restrict__ bo, const float* __restrict__ Wp,
    const float* __restrict__ bp,
    unsigned short* __restrict__ nfb, unsigned short* __restrict__ wfrag,
    float* __restrict__ wfold, float* __restrict__ c0, float* __restrict__ out,
    int* __restrict__ gcursor, int* __restrict__ binned,
    int nBin, int nE, int nbS, int out_size, int nNodes) {
    __shared__ int lhist[128], lbase[128], lofs[128], lcur[128];
    __shared__ int sortedV[BINCHUNK];      // 16 KB
    __shared__ int sortedA[BINCHUNK];      // 16 KB
    const int t = threadIdx.x;
    if ((int)blockIdx.x < nBin) {
        const int e0 = blockIdx.x * BINCHUNK;
        const int e1 = min(e0 + BINCHUNK, nE);
        const int cnt = e1 - e0;
        for (int i = t; i < 128; i += 256) lhist[i] = 0;
        __syncthreads();
        for (int e = e0 + t; e < e1; e += 256)
            atomicAdd(&lhist[dst[e] >> SBSH], 1);
        __syncthreads();
        if (t < 128) lofs[t] = lhist[t];
        __syncthreads();
        #pragma unroll
        for (int s = 1; s < 128; s <<= 1) {          // inclusive scan, 128 wide
            int v = 0;
            if (t < 128 && t >= s) v = lofs[t - s];
            __syncthreads();
            if (t < 128) lofs[t] += v;
            __syncthreads();
        }
        if (t < nbS) {
            int c = lhist[t];
            lbase[t] = c ? atomicAdd(&gcursor[t], c) : 0;
            lcur[t] = lofs[t] - c;                   // local exclusive offset
        }
        __syncthreads();
        for (int e = e0 + t; e < e1; e += 256) {     // sort into LDS staging
            int d = dst[e];
            int sb = d >> SBSH;
            int p = atomicAdd(&lcur[sb], 1);
            sortedV[p] = (src[e] << SBSH) | (d & (SBN - 1));
            int r = p - (lofs[sb] - lhist[sb]);      // rank within bucket
            int gp = lbase[sb] + r;
            sortedA[p] = (gp < SBCAP) ? (sb * SBCAP + gp) : -1;
        }
        __syncthreads();
        for (int i = t; i < cnt; i += 256) {         // streaming write-out
            int ga = sortedA[i];
            if (ga >= 0) binned[ga] = sortedV[i];
        }
        return;
    }
    // ---- prep part ----
    const int tp = ((int)blockIdx.x - nBin) * 256 + t;
    const int nth = ((int)gridDim.x - nBin) * 256;
    const float4* nf4 = (const float4*)nf;
    ushort4* nfb4 = (ushort4*)nfb;
    const int nQ = nNodes * 16;
    for (int i = tp; i < nQ; i += nth) {
        float4 v = nf4[i];
        ushort4 o;
        o.x = rne_bf16(v.x); o.y = rne_bf16(v.y);
        o.z = rne_bf16(v.z); o.w = rne_bf16(v.w);
        nfb4[i] = o;
    }
    const float* Ws[3] = {Wg, Wr, Wi};
    for (int idx = tp; idx < NWFRAG; idx += nth) {
        int j = idx & 7, lane = (idx >> 3) & 63, nt = (idx >> 9) & 3;
        int kt = (idx >> 11) & 1, part = (idx >> 12) & 1, mat = idx >> 13;
        int k = kt * 32 + ((lane >> 4) << 3) + j;
        int n = nt * 16 + (lane & 15);
        float w = Ws[mat][k * 64 + n];
        unsigned short hi = rne_bf16(w);
        wfrag[idx] = (part == 0) ? hi : rne_bf16(w - bf16_to_f(hi));
    }
    if (tp < 64) {
        float s = 0.f;
        for (int j = 0; j < 128; ++j) s += Wo[tp * 128 + j] * Wp[j];
        wfold[tp] = s;
    }
    if (tp == 0) {
        float s = 0.f;
        for (int j = 0; j < 128; ++j) s += bo[j] * Wp[j];
        c0[0] = s;
    }
    if (tp < out_size) out[tp] = bp[0];
}

// ---- segB: per-super-bucket CSR — LDS edge cache, hist+scan+in-place fill ---
__global__ __launch_bounds__(1024) void segB_kernel(
    int* __restrict__ binned, const int* __restrict__ gcursor,
    int2* __restrict__ nodeTab, int nNodes) {
    __shared__ int eL[SBCAP];                // 51 KB edge cache
    __shared__ int deg[SBN], sc[SBN], cur[SBN];
    const int b = blockIdx.x, t = threadIdx.x;
    const int cnt = min(gcursor[b], SBCAP);
    const int bb = b * SBCAP;
    deg[t] = 0;
    __syncthreads();
    for (int i = t; i < cnt; i += 1024) {
        int p = binned[bb + i];
        eL[i] = p;
        atomicAdd(&deg[p & (SBN - 1)], 1);
    }
    __syncthreads();
    sc[t] = deg[t];
    __syncthreads();
    #pragma unroll
    for (int s = 1; s < SBN; s <<= 1) {
        int v = (t >= s) ? sc[t - s] : 0;
        __syncthreads();
        sc[t] += v;
        __syncthreads();
    }
    {
        int excl = sc[t] - deg[t];
        cur[t] = excl;
        int node = b * SBN + t;
        if (node < nNodes) nodeTab[node] = make_int2(bb + excl, deg[t]);
    }
    __syncthreads();
    for (int i = t; i < cnt; i += 1024) {
        int p = eL[i];
        int pos = atomicAdd(&cur[p & (SBN - 1)], 1);
        binned[bb + pos] = p >> SBSH;
    }
}

// ---- gather: wave per node; prefetched indices -> 8 independent row loads ---
__global__ __launch_bounds__(256) void gather_kernel(
    const unsigned short* __restrict__ nfb, const int2* __restrict__ nodeTab,
    const int* __restrict__ srcs, unsigned short* __restrict__ aggb, int nNodes) {
    int wid = blockIdx.x * 4 + (threadIdx.x >> 6);
    if (wid >= nNodes) return;
    int lane = threadIdx.x & 63;
    int half = lane >> 5;             // edge parity
    int cp = lane & 31;               // channel pair (channels 2cp, 2cp+1)
    int2 sd = nodeTab[wid];
    int base = sd.x, d = sd.y;
    const ushort2* nfb2 = (const ushort2*)nfb;
    float ax = 0.f, ay = 0.f;
    if (d > 0 && d <= 64) {
        // one coalesced index load; rows via shfl'd in-register indices
        int myidx = srcs[base + min(lane, d - 1)];
        int dh = (d - half + 1) >> 1;             // my parity's edge count
        for (int jb = 0; jb < dh; jb += 8) {
            int sA[8];
            #pragma unroll
            for (int u = 0; u < 8; ++u) {
                int e = 2 * (jb + u) + half;
                sA[u] = __shfl(myidx, (e < d) ? e : (d - 1), 64);
            }
            ushort2 v[8];
            #pragma unroll
            for (int u = 0; u < 8; ++u)           // 8 independent loads
                v[u] = nfb2[(long)sA[u] * 32 + cp];
            #pragma unroll
            for (int u = 0; u < 8; ++u)
                if (jb + u < dh) { ax += bf16_to_f(v[u].x); ay += bf16_to_f(v[u].y); }
        }
    } else if (d > 64) {
        int k = half;
        for (; k + 8 <= d; k += 8) {
            int s0 = srcs[base + k],     s1 = srcs[base + k + 2];
            int s2 = srcs[base + k + 4], s3 = srcs[base + k + 6];
            ushort2 v0 = nfb2[(long)s0 * 32 + cp];
            ushort2 v1 = nfb2[(long)s1 * 32 + cp];
            ushort2 v2 = nfb2[(long)s2 * 32 + cp];
            ushort2 v3 = nfb2[(long)s3 * 32 + cp];
            ax += (bf16_to_f(v0.x) + bf16_to_f(v1.x)) + (bf16_to_f(v2.x) + bf16_to_f(v3.x));
            ay += (bf16_to_f(v0.y) + bf16_to_f(v1.y)) + (bf16_to_f(v2.y) + bf16_to_f(v3.y));
        }
        for (; k < d; k += 2) {
            int s = srcs[base + k];
            ushort2 v = nfb2[(long)s * 32 + cp];
            ax += bf16_to_f(v.x); ay += bf16_to_f(v.y);
        }
    }
    ax += __shfl_xor(ax, 32, 64);
    ay += __shfl_xor(ay, 32, 64);
    if (half == 0) {
        ushort2 o; o.x = rne_bf16(ax); o.y = rne_bf16(ay);
        ((ushort2*)aggb)[(long)wid * 32 + cp] = o;
    }
}

// ---- MFMA MLP: one wave = 32 nodes, bf16 A-frags direct from global --------
__global__ __launch_bounds__(256) void mlp_kernel(
    const unsigned short* __restrict__ aggb, const unsigned short* __restrict__ nfb,
    const int* __restrict__ gids, const unsigned short* __restrict__ wfrag,
    const float* __restrict__ bg, const float* __restrict__ br,
    const float* __restrict__ bi, const float* __restrict__ wfold,
    const float* __restrict__ c0p, float* __restrict__ out, int nTiles) {
    __shared__ float hs_all[4][32 * 68];
    const int wave = threadIdx.x >> 6, lane = threadIdx.x & 63;
    const int wid = blockIdx.x * 4 + wave;
    if (wid >= nTiles) return;
    float* hs = hs_all[wave];
    const int base = wid * 32;
    const int mrow = lane & 15, quad = lane >> 4;

    Frag aA[2][2], aN[2][2];
    #pragma unroll
    for (int rt = 0; rt < 2; ++rt) {
        const unsigned short* rowA = aggb + (long)(base + rt * 16 + mrow) * 64;
        const unsigned short* rowN = nfb  + (long)(base + rt * 16 + mrow) * 64;
        #pragma unroll
        for (int kt = 0; kt < 2; ++kt) {
            aA[rt][kt].b = *(const bf16x8*)(rowA + kt * 32 + quad * 8);
            aN[rt][kt].b = *(const bf16x8*)(rowN + kt * 32 + quad * 8);
        }
    }
    const unsigned short* wl0 = wfrag + lane * 8;
    auto WF = [&](int mat, int part, int kt, int nt) -> bf16x8 {
        return *(const bf16x8*)(wl0 + (size_t)((((mat * 2 + part) * 2 + kt) * 4 + nt) * 64) * 8);
    };
    f32x4 accA[2][4], accR[2][4];
    #pragma unroll
    for (int rt = 0; rt < 2; ++rt)
        #pragma unroll
        for (int nt = 0; nt < 4; ++nt) {
            accA[rt][nt] = (f32x4){0.f, 0.f, 0.f, 0.f};
            accR[rt][nt] = (f32x4){0.f, 0.f, 0.f, 0.f};
        }
    #pragma unroll
    for (int nt = 0; nt < 4; ++nt)
        #pragma unroll
        for (int kt = 0; kt < 2; ++kt) {
            bf16x8 gh = WF(0, 0, kt, nt), gl = WF(0, 1, kt, nt);
            bf16x8 rh = WF(1, 0, kt, nt), rl = WF(1, 1, kt, nt);
            #pragma unroll
            for (int rt = 0; rt < 2; ++rt) {
                accA[rt][nt] = MFMA16(aA[rt][kt].b, gh, accA[rt][nt], 0, 0, 0);
                accA[rt][nt] = MFMA16(aA[rt][kt].b, gl, accA[rt][nt], 0, 0, 0);
                accR[rt][nt] = MFMA16(aN[rt][kt].b, rh, accR[rt][nt], 0, 0, 0);
                accR[rt][nt] = MFMA16(aN[rt][kt].b, rl, accR[rt][nt], 0, 0, 0);
            }
        }
    #pragma unroll
    for (int nt = 0; nt < 4; ++nt) {
        float bgv = bg[nt * 16 + mrow], brv = br[nt * 16 + mrow];
        #pragma unroll
        for (int rt = 0; rt < 2; ++rt)
            #pragma unroll
            for (int r = 0; r < 4; ++r) {
                float h = fmaxf(accA[rt][nt][r] + bgv, 0.f)
                        + fmaxf(accR[rt][nt][r] + brv, 0.f);
                hs[(rt * 16 + quad * 4 + r) * 68 + nt * 16 + mrow] = h;
            }
    }
    __builtin_amdgcn_wave_barrier();
    Frag aH[2][2];
    #pragma unroll
    for (int rt = 0; rt < 2; ++rt)
        #pragma unroll
        for (int kt = 0; kt < 2; ++kt) {
            const float* hp = hs + (rt * 16 + mrow) * 68 + kt * 32 + quad * 8;
            float4 v0 = *(const float4*)hp;
            float4 v1 = *(const float4*)(hp + 4);
            aH[rt][kt].u[0] = rne_bf16(v0.x); aH[rt][kt].u[1] = rne_bf16(v0.y);
            aH[rt][kt].u[2] = rne_bf16(v0.z); aH[rt][kt].u[3] = rne_bf16(v0.w);
            aH[rt][kt].u[4] = rne_bf16(v1.x); aH[rt][kt].u[5] = rne_bf16(v1.y);
            aH[rt][kt].u[6] = rne_bf16(v1.z); aH[rt][kt].u[7] = rne_bf16(v1.w);
        }
    f32x4 accH[2][4];
    #pragma unroll
    for (int rt = 0; rt < 2; ++rt)
        #pragma unroll
        for (int nt = 0; nt < 4; ++nt)
            accH[rt][nt] = (f32x4){0.f, 0.f, 0.f, 0.f};
    #pragma unroll
    for (int nt = 0; nt < 4; ++nt)
        #pragma unroll
        for (int kt = 0; kt < 2; ++kt) {
            bf16x8 ih = WF(2, 0, kt, nt), il = WF(2, 1, kt, nt);
            #pragma unroll
            for (int rt = 0; rt < 2; ++rt) {
                accH[rt][nt] = MFMA16(aH[rt][kt].b, ih, accH[rt][nt], 0, 0, 0);
                accH[rt][nt] = MFMA16(aH[rt][kt].b, il, accH[rt][nt], 0, 0, 0);
            }
        }
    float p[2][4];
    #pragma unroll
    for (int rt = 0; rt < 2; ++rt)
        #pragma unroll
        for (int r = 0; r < 4; ++r) p[rt][r] = 0.f;
    #pragma unroll
    for (int nt = 0; nt < 4; ++nt) {
        float biv = bi[nt * 16 + mrow], wfv = wfold[nt * 16 + mrow];
        #pragma unroll
        for (int rt = 0; rt < 2; ++rt)
            #pragma unroll
            for (int r = 0; r < 4; ++r)
                p[rt][r] += fmaxf(accH[rt][nt][r] + biv, 0.f) * wfv;
    }
    #pragma unroll
    for (int m = 1; m <= 8; m <<= 1)
        #pragma unroll
        for (int rt = 0; rt < 2; ++rt)
            #pragma unroll
            for (int r = 0; r < 4; ++r)
                p[rt][r] += __shfl_xor(p[rt][r], m, 64);
    const float c0 = c0p[0];
    #pragma unroll
    for (int rt = 0; rt < 2; ++rt)
        #pragma unroll
        for (int r = 0; r < 4; ++r) p[rt][r] += c0;
    int gself = gids[base + (lane & 31)];
    int g0 = __shfl(gself, 0, 64);
    if (__all(gself == g0)) {
        float pv = 0.f;
        if (mrow == 0) {
            #pragma unroll
            for (int rt = 0; rt < 2; ++rt)
                #pragma unroll
                for (int r = 0; r < 4; ++r) pv += p[rt][r];
        }
        pv += __shfl_xor(pv, 16, 64);
        pv += __shfl_xor(pv, 32, 64);
        if (lane == 0) atomicAdd(out + g0, pv);
    } else if (mrow == 0) {
        #pragma unroll
        for (int rt = 0; rt < 2; ++rt)
            #pragma unroll
            for (int r = 0; r < 4; ++r)
                atomicAdd(out + gids[base + rt * 16 + quad * 4 + r], p[rt][r]);
    }
}

extern "C" void kernel_launch(void* const* d_in, const int* in_sizes, int n_in,
                              void* d_out, int out_size, void* d_ws, size_t ws_size,
                              hipStream_t stream) {
    const float* node_feats = (const float*)d_in[0];
    const int* src  = (const int*)d_in[2];
    const int* dst  = (const int*)d_in[3];
    const int* gids = (const int*)d_in[4];
    const float* Wg = (const float*)d_in[5];
    const float* bg = (const float*)d_in[6];
    const float* Wr = (const float*)d_in[7];
    const float* br = (const float*)d_in[8];
    const float* Wi = (const float*)d_in[9];
    const float* bi = (const float*)d_in[10];
    const float* Wo = (const float*)d_in[11];
    const float* bo = (const float*)d_in[12];
    const float* Wp = (const float*)d_in[13];
    const float* bp = (const float*)d_in[14];
    float* out = (float*)d_out;

    const int nNodes = in_sizes[0] / 64;              // 100000
    const int nE = in_sizes[2];
    const int nbS = (nNodes + SBN - 1) / SBN;         // 98
    const int nBin = (nE + BINCHUNK - 1) / BINCHUNK;  // 293
    const int nTiles = (nNodes + 31) / 32;            // 3125

    // ws: gcursor[128] | binned[nbS*SBCAP] | nodeTab[N] int2 | nfb | aggb | wfrag | wfold | c0
    int* gcursor = (int*)d_ws;
    int* binned  = gcursor + 128;
    int2* nodeTab = (int2*)(binned + (size_t)nbS * SBCAP);
    unsigned short* nfb  = (unsigned short*)(nodeTab + nNodes);
    unsigned short* aggb = nfb + (size_t)nNodes * 64;
    unsigned short* wfrag = aggb + (size_t)nNodes * 64;
    float* wfold = (float*)(wfrag + NWFRAG);
    float* c0 = wfold + 64;

    hipMemsetAsync(gcursor, 0, 128 * sizeof(int), stream);

    prepbinA_kernel<<<nBin + 512, 256, 0, stream>>>(
        node_feats, src, dst, Wg, Wr, Wi, Wo, bo, Wp, bp,
        nfb, wfrag, wfold, c0, out, gcursor, binned,
        nBin, nE, nbS, out_size, nNodes);

    segB_kernel<<<nbS, 1024, 0, stream>>>(binned, gcursor, nodeTab, nNodes);

    gather_kernel<<<(nNodes + 3) / 4, 256, 0, stream>>>(nfb, nodeTab, binned, aggb, nNodes);

    mlp_kernel<<<(nTiles + 3) / 4, 256, 0, stream>>>(aggb, nfb, gids, wfrag,
        bg, br, bi, wfold, c0, out, nTiles);
}